// Round 8
// baseline (270.568 us; speedup 1.0000x reference)
//
#include <hip/hip_runtime.h>

#define C_DIM 256
#define K_DIM 128
#define HW_DIM 64
#define PIX 4096
#define N_IMG 32

using short8 = __attribute__((ext_vector_type(8))) short;
using f32x4  = __attribute__((ext_vector_type(4))) float;

__device__ __forceinline__ unsigned long long umin64(unsigned long long a, unsigned long long b) {
    return a < b ? a : b;
}
__device__ __forceinline__ unsigned mono(float d) {
    unsigned u = __float_as_uint(d);
    return u ^ ((u & 0x80000000u) ? 0xFFFFFFFFu : 0x80000000u);
}

// Truncation split: v = hi + mid + lo (exact Sterbenz residuals). and/sub only.
__device__ __forceinline__ void split3t(float v, unsigned& hu, unsigned& mu, unsigned& lu) {
    unsigned u = __float_as_uint(v);
    float r1 = v - __uint_as_float(u & 0xffff0000u);
    unsigned r1u = __float_as_uint(r1);
    float r2 = r1 - __uint_as_float(r1u & 0xffff0000u);
    hu = u; mu = r1u; lu = __float_as_uint(r2);   // consumers take >>16
}

// P: per cluster k: trunc 3-way split -> Bt[k][768] (planes hi/mid/lo) + exact c2
__global__ __launch_bounds__(64) void prep_kernel(const float* __restrict__ cl,
                                                  unsigned short* __restrict__ Bt,
                                                  float* __restrict__ c2) {
    int k = blockIdx.x;
    int lane = threadIdx.x;
    const float4* row = (const float4*)(cl + k * C_DIM);
    float4 v = row[lane];
    float vv[4] = {v.x, v.y, v.z, v.w};
    unsigned short* bk = Bt + k * 768 + lane * 4;
#pragma unroll
    for (int i = 0; i < 4; ++i) {
        unsigned hu, mu, lu;
        split3t(vv[i], hu, mu, lu);
        bk[i]       = (unsigned short)(hu >> 16);
        bk[256 + i] = (unsigned short)(mu >> 16);
        bk[512 + i] = (unsigned short)(lu >> 16);
    }
    if (lane == 0) {   // identical op order to proven-exact c2
        float s = 0.f;
#pragma unroll
        for (int i = 0; i < C_DIM / 4; ++i) {
            float4 u = row[i];
            s = fmaf(u.x, u.x, s);
            s = fmaf(u.y, u.y, s);
            s = fmaf(u.z, u.z, s);
            s = fmaf(u.w, u.w, s);
        }
        c2[k] = s;
    }
}

// Main: barrier-free K-loop. Block = 4 waves; wave (pg, kj) owns px-group
// pg (32 px) x cluster-half kj (64 k). A-fragments built IN REGISTERS from
// natural x loads (lane(q,l15): px = mt*16+l15, ch = q*8+j == A-frag layout).
// B-fragments from L2-hot Bt. acc = 2mt x 4nt x f32x4 = 32 AGPR.
// Per-acc MFMA term order (ci-major; pa=0:pb012, pa=1:pb01, pa=2:pb0) is
// bit-identical to proven rounds 5-7. Epilogue: shfl x2/argmin + 1KB LDS
// k-half merge + fused histogram via exact 1/64 fp32 atomics.
__global__ __launch_bounds__(256, 4) void main_kernel(
    const float* __restrict__ x, const unsigned short* __restrict__ Bt,
    const float* __restrict__ c2v, float* __restrict__ out) {

    __shared__ unsigned long long red[2][64];

    const int t    = threadIdx.x;
    const int lane = t & 63;
    const int w    = t >> 6;
    const int pg   = w >> 1;          // pixel-group (0/1)
    const int kj   = w & 1;           // cluster-half (0/1)
    const int q    = lane >> 4;
    const int l15  = lane & 15;

    const int b   = blockIdx.x;       // 2048 blocks x 64 px
    const int img = b >> 6;
    const int row = b & 63;           // row within image

    const float* xg = x + (size_t)img * (C_DIM * PIX) + row * HW_DIM + pg * 32 + l15;

    const unsigned short* bq0 = Bt + (size_t)(kj * 64 +  0 + l15) * 768 + q * 8;
    const unsigned short* bq1 = Bt + (size_t)(kj * 64 + 16 + l15) * 768 + q * 8;
    const unsigned short* bq2 = Bt + (size_t)(kj * 64 + 32 + l15) * 768 + q * 8;
    const unsigned short* bq3 = Bt + (size_t)(kj * 64 + 48 + l15) * 768 + q * 8;

    f32x4 acc[2][4];
#pragma unroll
    for (int mt = 0; mt < 2; ++mt)
#pragma unroll
        for (int nt = 0; nt < 4; ++nt) acc[mt][nt] = (f32x4){0.f, 0.f, 0.f, 0.f};

    float x2m[2] = {0.f, 0.f};

    float xv[2][8];
#pragma unroll
    for (int mt = 0; mt < 2; ++mt)
#pragma unroll
        for (int j = 0; j < 8; ++j)
            xv[mt][j] = xg[(size_t)(q * 8 + j) * PIX + mt * 16];

#pragma unroll 1
    for (int ci = 0; ci < 8; ++ci) {
        // ---- build A-fragments in registers (trunc split) + x2 ----
        union U { unsigned u[4]; short8 s; };
        short8 af[3][2];
#pragma unroll
        for (int mt = 0; mt < 2; ++mt) {
            U ah, am, al;
#pragma unroll
            for (int jj = 0; jj < 4; ++jj) {
                float v0 = xv[mt][2 * jj], v1 = xv[mt][2 * jj + 1];
                unsigned h0, m0, l0, h1, m1, l1;
                split3t(v0, h0, m0, l0);
                split3t(v1, h1, m1, l1);
                ah.u[jj] = (h0 >> 16) | (h1 & 0xffff0000u);
                am.u[jj] = (m0 >> 16) | (m1 & 0xffff0000u);
                al.u[jj] = (l0 >> 16) | (l1 & 0xffff0000u);
                x2m[mt] = fmaf(v0, v0, x2m[mt]);
                x2m[mt] = fmaf(v1, v1, x2m[mt]);
            }
            af[0][mt] = ah.s; af[1][mt] = am.s; af[2][mt] = al.s;
        }

        // ---- issue next chunk's x loads (hidden behind MFMA phase) ----
        if (ci < 7) {
#pragma unroll
            for (int mt = 0; mt < 2; ++mt)
#pragma unroll
                for (int j = 0; j < 8; ++j)
                    xv[mt][j] = xg[(size_t)((ci + 1) * 32 + q * 8 + j) * PIX + mt * 16];
        }

        // ---- nt-half 0 (nt = 0,1): 6 B-frags, then MFMAs (pa-major) ----
        {
            short8 bf[3][2];
#pragma unroll
            for (int p = 0; p < 3; ++p) {
                bf[p][0] = *(const short8*)(bq0 + p * 256 + ci * 32);
                bf[p][1] = *(const short8*)(bq1 + p * 256 + ci * 32);
            }
#pragma unroll
            for (int pa = 0; pa < 3; ++pa)
#pragma unroll
                for (int mt = 0; mt < 2; ++mt)
#pragma unroll
                    for (int ntl = 0; ntl < 2; ++ntl)
#pragma unroll
                        for (int pb2 = 0; pb2 < 3; ++pb2)
                            if (pb2 < 3 - pa)
                                acc[mt][ntl] = __builtin_amdgcn_mfma_f32_16x16x32_bf16(
                                    af[pa][mt], bf[pb2][ntl], acc[mt][ntl], 0, 0, 0);
        }
        // ---- nt-half 1 (nt = 2,3) ----
        {
            short8 bf[3][2];
#pragma unroll
            for (int p = 0; p < 3; ++p) {
                bf[p][0] = *(const short8*)(bq2 + p * 256 + ci * 32);
                bf[p][1] = *(const short8*)(bq3 + p * 256 + ci * 32);
            }
#pragma unroll
            for (int pa = 0; pa < 3; ++pa)
#pragma unroll
                for (int mt = 0; mt < 2; ++mt)
#pragma unroll
                    for (int ntl = 0; ntl < 2; ++ntl)
#pragma unroll
                        for (int pb2 = 0; pb2 < 3; ++pb2)
                            if (pb2 < 3 - pa)
                                acc[mt][2 + ntl] = __builtin_amdgcn_mfma_f32_16x16x32_bf16(
                                    af[pa][mt], bf[pb2][ntl], acc[mt][2 + ntl], 0, 0, 0);
        }
    }

    // ---- x2: 4-way tree across q-groups (lanes l15+16q share px mt*16+l15) ----
#pragma unroll
    for (int mt = 0; mt < 2; ++mt) {
        float s = x2m[mt];
        s += __shfl_xor(s, 16);
        s += __shfl_xor(s, 32);
        x2m[mt] = s;
    }

    float c2l[4];
#pragma unroll
    for (int nt = 0; nt < 4; ++nt) c2l[nt] = c2v[kj * 64 + nt * 16 + l15];

    // ---- dist + in-wave argmin; C/D: col(lane&15)=cluster, row(q*4+r)=px ----
#pragma unroll
    for (int mt = 0; mt < 2; ++mt) {
#pragma unroll
        for (int r = 0; r < 4; ++r) {
            float x2v = __shfl(x2m[mt], q * 4 + r);   // px = mt*16 + q*4 + r
            unsigned long long best = ~0ull;
#pragma unroll
            for (int nt = 0; nt < 4; ++nt) {
                float d = (x2v - 2.0f * acc[mt][nt][r]) + c2l[nt];
                unsigned long long key = ((unsigned long long)mono(d) << 32)
                                       | (unsigned)(kj * 64 + nt * 16 + l15);
                best = umin64(best, key);
            }
            best = umin64(best, __shfl_xor(best, 1));
            best = umin64(best, __shfl_xor(best, 2));
            best = umin64(best, __shfl_xor(best, 4));
            best = umin64(best, __shfl_xor(best, 8));
            if (l15 == 0) red[kj][pg * 32 + mt * 16 + q * 4 + r] = best;
        }
    }
    __syncthreads();

    // ---- k-half merge + fused histogram (1/64 adds are exact in fp32) ----
    if (t < 64) {
        unsigned long long mk = umin64(red[0][t], red[1][t]);
        int cl = (int)(mk & 0xFFu);
        int tile = (row >> 3) * 8 + (t >> 3);
        atomicAdd(out + ((size_t)img * 64 + tile) * (K_DIM + 1) + cl + 1, 0.015625f);
    }
}

extern "C" void kernel_launch(void* const* d_in, const int* in_sizes, int n_in,
                              void* d_out, int out_size, void* d_ws, size_t ws_size,
                              hipStream_t stream) {
    const float* x  = (const float*)d_in[0];       // (32, 256, 64, 64) fp32
    const float* cl = (const float*)d_in[1];       // (128, 256) fp32
    float* out = (float*)d_out;                    // (32, 64, 129) fp32

    unsigned short* Bt = (unsigned short*)d_ws;                  // 196608 B
    float* c2 = (float*)((char*)d_ws + 196608);                  // 512 B

    hipMemsetAsync(out, 0, (size_t)out_size * sizeof(float), stream);
    prep_kernel<<<K_DIM, 64, 0, stream>>>(cl, Bt, c2);
    main_kernel<<<(N_IMG * PIX) / 64, 256, 0, stream>>>(x, Bt, c2, out);
}